// Round 18
// baseline (674.689 us; speedup 1.0000x reference)
//
#include <hip/hip_runtime.h>
#include <stdint.h>

typedef __attribute__((ext_vector_type(8))) short bf16x8;
typedef __attribute__((ext_vector_type(4))) short s16x4;
typedef __attribute__((ext_vector_type(4))) float f32x4;

__device__ __forceinline__ short f2bf(float f){
  unsigned x = __float_as_uint(f);
  unsigned r = (x + 0x7fffu + ((x >> 16) & 1u)) >> 16;
  return (short)r;
}

// async global->LDS, 16B per lane (dest = wave-uniform base + lane*16)
__device__ __forceinline__ void g2l16(const void* g, void* l){
  __builtin_amdgcn_global_load_lds(
      (const __attribute__((address_space(1))) unsigned int*)(unsigned long long)(uintptr_t)g,
      (__attribute__((address_space(3))) unsigned int*)(unsigned int)(uintptr_t)l,
      16, 0, 0);
}

// ---------------------------------------------------------------------------
// Pack 8 weights (f32, 1024x1024 row-major K x N) into bf16 tiles.
// W0 (Wq) pre-scaled by 1/sqrt(DK)=0.125 (exact pow2 -> same bf16 rounding).
// ---------------------------------------------------------------------------
struct W8 { const float* w[8]; };
__global__ __launch_bounds__(256) void pack_w8(W8 ws8, short* __restrict__ out){
  const int m = blockIdx.y;
  const float scl = (m == 0) ? 0.125f : 1.0f;
  const float* __restrict__ W = ws8.w[m];
  short* o = out + (size_t)m * 1048576 + (size_t)blockIdx.x * 4096;
  const int kt = blockIdx.x & 31, nt = blockIdx.x >> 5;
  const int t = threadIdx.x;
  #pragma unroll
  for (int i = 0; i < 16; ++i){
    int flat = i * 256 + t;              // 0..4095
    int kl = flat >> 7;                  // /128
    int nl = flat & 127;
    o[nl * 32 + kl] = f2bf(W[(size_t)(kt * 32 + kl) * 1024 + nt * 128 + nl] * scl);
  }
}

// ---------------------------------------------------------------------------
// Heterogeneous batched kernel: per-z action
//   act 0..3  : n-PAIRED GEMM segment: one staged A serves TWO adjacent
//               128-n tiles (y in 0..3 -> n0 = y*256). 32 MFMA per barrier,
//               A HBM traffic halved vs 1-tile blocks. dbuf 2-phase K-loop.
//   act 4..7  : f32->bf16 convert segment (grid-stride)
//   act 8 / 9 : mask||pad -> bitmask (e / ei)
// GEMM om: 0 = C bf16 row-major, 1 = C bf16 as (B,H=16,DK=64,S), 2 = C f32.
// ---------------------------------------------------------------------------
struct GSeg { const short* A; const short* Wp; const float* bias; void* C;
              int om; int S; int mt; float bs; };
struct Big {
  GSeg g[4];
  const float* cin[4]; short* cout[4]; int n8[4];
  const int* me; const int* pe; unsigned* be;
  const int* mi; const int* pi; unsigned* bi;
  int act[8];
};

__device__ __forceinline__ void gemm_core(const GSeg sg,
                                          short (*sA)[4096],
                                          short (*sB)[2][4096]){
  if ((int)blockIdx.x >= sg.mt) return;
  const int t = threadIdx.x;
  const int m0 = blockIdx.x * 128;
  const int nyy = blockIdx.y;            // 0..3 (pair index)
  const int n0 = nyy * 256;
  const int w = t >> 6, lane = t & 63, lr = lane & 15, lg = lane >> 4;
  const int wm = (w >> 1) * 64, wn = (w & 1) * 64;

  const int arow  = t >> 2;
  const int acol8 = (t & 3) * 8;
  const short* Ag  = sg.A + (size_t)(m0 + arow) * 1024 + acol8;
  const short* Bg0 = sg.Wp + (size_t)(nyy * 2) * 32 * 4096 + t * 8;
  const short* Bg1 = Bg0 + 131072;       // next 128-n tile (32*4096 elems)

  f32x4 acc[2][4][4] = {};

  // prologue: stage tile 0 into buffer 0
  g2l16(Ag, sA[0] + t * 8);
  g2l16(Ag + 64 * 1024, sA[0] + 2048 + t * 8);
  g2l16(Bg0, sB[0][0] + t * 8);
  g2l16(Bg0 + 2048, sB[0][0] + 2048 + t * 8);
  g2l16(Bg1, sB[0][1] + t * 8);
  g2l16(Bg1 + 2048, sB[0][1] + 2048 + t * 8);

  int cur = 0;
  for (int kt = 0; kt < 32; ++kt){
    __syncthreads();                     // drains vmcnt -> buf[cur] ready
    if (kt < 31){                        // issue next tile into buf[cur^1]
      const int kn = kt + 1;
      g2l16(Ag + kn * 32, sA[cur ^ 1] + t * 8);
      g2l16(Ag + 64 * 1024 + kn * 32, sA[cur ^ 1] + 2048 + t * 8);
      const short* b0 = Bg0 + (size_t)kn * 4096;
      g2l16(b0, sB[cur ^ 1][0] + t * 8);
      g2l16(b0 + 2048, sB[cur ^ 1][0] + 2048 + t * 8);
      const short* b1 = Bg1 + (size_t)kn * 4096;
      g2l16(b1, sB[cur ^ 1][1] + t * 8);
      g2l16(b1 + 2048, sB[cur ^ 1][1] + 2048 + t * 8);
    }

    bf16x8 af[4];
    #pragma unroll
    for (int mi = 0; mi < 4; ++mi)
      af[mi] = *(const bf16x8*)&sA[cur][(wm + mi * 16 + lr) * 32 + lg * 8];
    #pragma unroll
    for (int p = 0; p < 2; ++p){
      bf16x8 bfr[4];
      #pragma unroll
      for (int ni = 0; ni < 4; ++ni)
        bfr[ni] = *(const bf16x8*)&sB[cur][p][(wn + ni * 16 + lr) * 32 + lg * 8];
      #pragma unroll
      for (int mi = 0; mi < 4; ++mi)
        #pragma unroll
        for (int ni = 0; ni < 4; ++ni)
          acc[p][mi][ni] = __builtin_amdgcn_mfma_f32_16x16x32_bf16(
              af[mi], bfr[ni], acc[p][mi][ni], 0, 0, 0);
    }
    cur ^= 1;
  }

  #pragma unroll
  for (int p = 0; p < 2; ++p){
    #pragma unroll
    for (int ni = 0; ni < 4; ++ni){
      const int n = n0 + p * 128 + wn + ni * 16 + lr;
      const float bv = sg.bias[n] * sg.bs;
      #pragma unroll
      for (int mi = 0; mi < 4; ++mi){
        const int mb = m0 + wm + mi * 16 + lg * 4;
        if (sg.om == 0){
          short* C = (short*)sg.C;
          #pragma unroll
          for (int j = 0; j < 4; ++j)
            C[(size_t)(mb + j) * 1024 + n] = f2bf(acc[p][mi][ni][j] + bv);
        } else if (sg.om == 1){
          short* C = (short*)sg.C;
          const int bb = mb / sg.S, sb = mb % sg.S;
          const int hh = n >> 6, dk = n & 63;
          s16x4 pk;
          #pragma unroll
          for (int j = 0; j < 4; ++j) pk[j] = f2bf(acc[p][mi][ni][j] + bv);
          *(s16x4*)&C[(((size_t)bb * 16 + hh) * 64 + dk) * sg.S + sb] = pk;
        } else {
          float* C = (float*)sg.C;
          #pragma unroll
          for (int j = 0; j < 4; ++j)
            C[(size_t)(mb + j) * 1024 + n] = acc[p][mi][ni][j] + bv;
        }
      }
    }
  }
}

__device__ __forceinline__ void cvt_core(const float* __restrict__ in,
                                         short* __restrict__ out, int n8){
  const long long total = (long long)gridDim.x * gridDim.y * 256;
  for (long long i = (long long)(blockIdx.y * gridDim.x + blockIdx.x) * 256 + threadIdx.x;
       i < n8; i += total){
    const float4* p = (const float4*)in + i * 2;
    const float4 a = p[0], b = p[1];
    bf16x8 v;
    v[0] = f2bf(a.x); v[1] = f2bf(a.y); v[2] = f2bf(a.z); v[3] = f2bf(a.w);
    v[4] = f2bf(b.x); v[5] = f2bf(b.y); v[6] = f2bf(b.z); v[7] = f2bf(b.w);
    *(bf16x8*)(out + i * 8) = v;
  }
}

__device__ __forceinline__ void bits_core(const int* __restrict__ mask,
                                          const int* __restrict__ pad,
                                          unsigned* __restrict__ bits,
                                          int SK, int nsb, int nunits){
  const int nb = gridDim.x * gridDim.y;
  for (int u = blockIdx.y * gridDim.x + blockIdx.x; u < nunits; u += nb){
    const int row = u / nsb, sb = u - row * nsb;   // row = b*512+q
    const int s = sb * 256 + threadIdx.x;
    const int b = row >> 9;
    const bool v = (mask[(size_t)row * SK + s] != 0) || (pad[(size_t)b * SK + s] != 0);
    unsigned long long bal = __ballot(v);
    const int lane = threadIdx.x & 63;
    if ((lane & 31) == 0)
      bits[((size_t)row * SK + s) >> 5] = (unsigned)(bal >> (lane & 32));
  }
}

__global__ __launch_bounds__(256) void mixk(Big big){
  __shared__ short sA[2][4096];
  __shared__ short sB[2][2][4096];
  const int a = big.act[blockIdx.z];
  if (a < 4)       gemm_core(big.g[a], sA, sB);
  else if (a < 8)  cvt_core(big.cin[a - 4], big.cout[a - 4], big.n8[a - 4]);
  else if (a == 8) bits_core(big.me, big.pe, big.be, 512, 2, 16384);
  else             bits_core(big.mi, big.pi, big.bi, 768, 3, 24576);
}

// ---------------------------------------------------------------------------
// One attention modality (8-wave block, 128 q-rows), accumulating wgt*O into
// tot. K/V staging double-buffered (R14-verified; NO setprio -- lockstep
// 8-wave blocks are the m190 regime where it hurts). Even NT => phase
// prologues target buf0 with no cross-phase WAR.
// No-max softmax (Q pre-scaled by 0.125; masked -1e30 -> exp == 0; l==0
// guarded). aw stores nontemporal.
// SINGLE=false: two-phase (P1: l only; P2: recompute + aw + PV). aw written.
// SINGLE=true : single-pass, no aw, unnormalized PV, normalize at end.
// ---------------------------------------------------------------------------
template<int SK, bool HAS_BIAS, bool SINGLE>
__device__ __forceinline__ void attn_mod(
    const short* __restrict__ Kp, const short* __restrict__ Vt,
    const unsigned* __restrict__ bits, float* __restrict__ aw,
    const bf16x8 (&qf)[2], f32x4 (&tot)[4], float wgt,
    short* sK, short* sV, short* sPw,
    int b, int h, int qw, int w, int lane, int lr, int lg){
  constexpr int NT  = SK / 128;
  constexpr int SKW = SK / 32;
  static_assert((NT & 1) == 0, "buffer-parity argument needs even NT");

  const int kchunk = (lane & 7) ^ ((lane >> 3) & 7);
  const short* Ksrc = Kp + ((size_t)b * SK + w * 16 + (lane >> 3)) * 1024 + h * 64 + kchunk * 8;
  const short* Vsrc = Vt + ((size_t)(b * 16 + h)) * 64 * SK;
  const int ldoff = w * 1024 + lane * 8;

  const unsigned* bitrow[4];
  if (HAS_BIAS){
    #pragma unroll
    for (int j = 0; j < 4; ++j)
      bitrow[j] = bits + ((size_t)(b * 512 + qw + lg * 4 + j)) * SKW;
  }

  float lrow[4];
  #pragma unroll
  for (int j = 0; j < 4; ++j) lrow[j] = 0.f;
  f32x4 acco[4] = {};

#define SKB(c) (sK + (c) * 8192)
#define SVB(c) (sV + (c) * 8192)
#define STAGE_K(c, s0) do{ \
    g2l16(Ksrc + (size_t)(s0) * 1024, SKB(c) + ldoff); \
    g2l16(Ksrc + (size_t)((s0) + 8) * 1024, SKB(c) + ldoff + 512); }while(0)
#define STAGE_V(c, s0) do{ \
    const int dd0 = w * 8 + (lane >> 4); \
    const int cg0 = (lane & 15) ^ (dd0 & 15); \
    g2l16(Vsrc + (size_t)dd0 * SK + (s0) + cg0 * 8, SVB(c) + ldoff); \
    const int dd1 = dd0 + 4; \
    const int cg1 = (lane & 15) ^ (dd1 & 15); \
    g2l16(Vsrc + (size_t)dd1 * SK + (s0) + cg1 * 8, SVB(c) + ldoff + 512); }while(0)

  if (!SINGLE){
    // ---------------- Phase 1: row-sum l only (K dbuf) ----------------
    STAGE_K(0, 0);
    int cur = 0;
    for (int tt = 0; tt < NT; ++tt){
      __syncthreads();                    // buf[cur] ready
      if (tt + 1 < NT) STAGE_K(cur ^ 1, (tt + 1) * 128);
      const short* kb = SKB(cur);

      f32x4 accs[8];
      #pragma unroll
      for (int si = 0; si < 8; ++si){
        f32x4 a = {};
        #pragma unroll
        for (int dt = 0; dt < 2; ++dt){
          bf16x8 kf = *(const bf16x8*)&kb[(si * 16 + lr) * 64 + ((dt * 4 + lg) ^ (lr & 7)) * 8];
          a = __builtin_amdgcn_mfma_f32_16x16x32_bf16(qf[dt], kf, a, 0, 0, 0);
        }
        accs[si] = a;
      }

      #pragma unroll
      for (int j = 0; j < 4; ++j){
        unsigned wb[4];
        if (HAS_BIAS){
          #pragma unroll
          for (int sp = 0; sp < 4; ++sp) wb[sp] = bitrow[j][tt * 4 + sp];
        }
        float ssum = 0.f;
        #pragma unroll
        for (int si = 0; si < 8; ++si){
          float v = accs[si][j];
          if (HAS_BIAS && ((wb[si >> 1] >> ((si & 1) * 16 + lr)) & 1u)) v = -1e30f;
          ssum += __expf(v);
        }
        lrow[j] += ssum;
      }
      cur ^= 1;
    }

    // merge l across the 16 lr lanes
    #pragma unroll
    for (int j = 0; j < 4; ++j){
      #pragma unroll
      for (int d = 1; d < 16; d <<= 1) lrow[j] += __shfl_xor(lrow[j], d);
    }
    float rinv[4];
    #pragma unroll
    for (int j = 0; j < 4; ++j) rinv[j] = lrow[j] > 0.f ? 1.0f / lrow[j] : 0.f;

    // ---------------- Phase 2: aw + PV (K+V dbuf) ----------------
    STAGE_K(0, 0);
    STAGE_V(0, 0);
    cur = 0;
    for (int tt = 0; tt < NT; ++tt){
      const int s0 = tt * 128;
      __syncthreads();
      if (tt + 1 < NT){ STAGE_K(cur ^ 1, s0 + 128); STAGE_V(cur ^ 1, s0 + 128); }
      const short* kb = SKB(cur);
      const short* vb = SVB(cur);

      f32x4 accs[8];
      #pragma unroll
      for (int si = 0; si < 8; ++si){
        f32x4 a = {};
        #pragma unroll
        for (int dt = 0; dt < 2; ++dt){
          bf16x8 kf = *(const bf16x8*)&kb[(si * 16 + lr) * 64 + ((dt * 4 + lg) ^ (lr & 7)) * 8];
          a = __builtin_amdgcn_mfma_f32_16x16x32_bf16(qf[dt], kf, a, 0, 0, 0);
        }
        accs[si] = a;
      }

      #pragma unroll
      for (int half = 0; half < 2; ++half){
        #pragma unroll
        for (int j = 0; j < 4; ++j){
          unsigned wb[2];
          if (HAS_BIAS){
            #pragma unroll
            for (int sp = 0; sp < 2; ++sp) wb[sp] = bitrow[j][tt * 4 + half * 2 + sp];
          }
          const int qq = lg * 4 + j;
          float* awrow = aw + (((size_t)(b * 16 + h)) * 512 + qw + qq) * SK + s0 + half * 64 + lr;
          #pragma unroll
          for (int si2 = 0; si2 < 4; ++si2){
            const int si = half * 4 + si2;
            float v = accs[si][j];
            if (HAS_BIAS && ((wb[si2 >> 1] >> ((si2 & 1) * 16 + lr)) & 1u)) v = -1e30f;
            const float p = __expf(v) * rinv[j];
            __builtin_nontemporal_store(p, &awrow[si2 * 16]);
            sPw[qq * 64 + (((si2 * 2 + (lr >> 3)) ^ (qq & 7)) * 8) + (lr & 7)] = f2bf(p);
          }
        }
        // PV half (same-wave LDS write->read; DS ops are in-order)
        #pragma unroll
        for (int kt2 = 0; kt2 < 2; ++kt2){
          const int kt = half * 2 + kt2;
          bf16x8 pa = *(const bf16x8*)&sPw[lr * 64 + (((kt2 * 4 + lg) ^ (lr & 7)) * 8)];
          #pragma unroll
          for (int ni = 0; ni < 4; ++ni){
            bf16x8 vf = *(const bf16x8*)&vb[(ni * 16 + lr) * 128 + ((kt * 4 + lg) ^ lr) * 8];
            acco[ni] = __builtin_amdgcn_mfma_f32_16x16x32_bf16(pa, vf, acco[ni], 0, 0, 0);
          }
        }
      }
      cur ^= 1;
    }

    #pragma unroll
    for (int ni = 0; ni < 4; ++ni)
      #pragma unroll
      for (int j = 0; j < 4; ++j)
        tot[ni][j] += wgt * acco[ni][j];
  } else {
    // ---------------- single-pass, unnormalized PV (K+V dbuf) ----------------
    STAGE_K(0, 0);
    STAGE_V(0, 0);
    int cur = 0;
    for (int tt = 0; tt < NT; ++tt){
      const int s0 = tt * 128;
      __syncthreads();
      if (tt + 1 < NT){ STAGE_K(cur ^ 1, s0 + 128); STAGE_V(cur ^ 1, s0 + 128); }
      const short* kb = SKB(cur);
      const short* vb = SVB(cur);

      f32x4 accs[8];
      #pragma unroll
      for (int si = 0; si < 8; ++si){
        f32x4 a = {};
        #pragma unroll
        for (int dt = 0; dt < 2; ++dt){
          bf16x8 kf = *(const bf16x8*)&kb[(si * 16 + lr) * 64 + ((dt * 4 + lg) ^ (lr & 7)) * 8];
          a = __builtin_amdgcn_mfma_f32_16x16x32_bf16(qf[dt], kf, a, 0, 0, 0);
        }
        accs[si] = a;
      }

      #pragma unroll
      for (int half = 0; half < 2; ++half){
        #pragma unroll
        for (int j = 0; j < 4; ++j){
          unsigned wb[2];
          if (HAS_BIAS){
            #pragma unroll
            for (int sp = 0; sp < 2; ++sp) wb[sp] = bitrow[j][tt * 4 + half * 2 + sp];
          }
          const int qq = lg * 4 + j;
          float ls = 0.f;
          #pragma unroll
          for (int si2 = 0; si2 < 4; ++si2){
            const int si = half * 4 + si2;
            float v = accs[si][j];
            if (HAS_BIAS && ((wb[si2 >> 1] >> ((si2 & 1) * 16 + lr)) & 1u)) v = -1e30f;
            const float p = __expf(v);
            ls += p;
            sPw[qq * 64 + (((si2 * 2 + (lr >> 3)) ^ (qq & 7)) * 8) + (lr & 7)] = f2bf(p);
          }
          lrow[j] += ls;
        }
        #pragma unroll
        for (int kt2 = 0; kt2 < 2; ++kt2){
          const int kt = half * 2 + kt2;
          bf16x8 pa = *(const bf16x8*)&sPw[lr * 64 + (((kt2 * 4 + lg) ^ (lr & 7)) * 8)];
          #pragma unroll
          for (int ni = 0; ni < 4; ++ni){
            bf16x8 vf = *(const bf16x8*)&vb[(ni * 16 + lr) * 128 + ((kt * 4 + lg) ^ lr) * 8];
            acco[ni] = __builtin_amdgcn_mfma_f32_16x16x32_bf16(pa, vf, acco[ni], 0, 0, 0);
          }
        }
      }
      cur ^= 1;
    }

    // final normalize
    #pragma unroll
    for (int j = 0; j < 4; ++j){
      #pragma unroll
      for (int d = 1; d < 16; d <<= 1) lrow[j] += __shfl_xor(lrow[j], d);
      const float r = lrow[j] > 0.f ? wgt / lrow[j] : 0.f;
      #pragma unroll
      for (int ni = 0; ni < 4; ++ni) tot[ni][j] += r * acco[ni][j];
    }
  }
#undef SKB
#undef SVB
#undef STAGE_K
#undef STAGE_V
}

// ---------------------------------------------------------------------------
// Fused attention: all three modalities per block; concat written directly.
// Block = (b, h, 128 q-rows), 8 waves, 512 threads, 80 KB LDS (2 blocks/CU).
// XCD-aware bid decode: same-(b,h) blocks differ by 256 (= 0 mod 8).
// ---------------------------------------------------------------------------
__global__ __launch_bounds__(512)
void attn_fused(const short* __restrict__ Qp,
                const short* __restrict__ Kep, const short* __restrict__ Vte,
                const unsigned* __restrict__ bits_e, float* __restrict__ aw_e,
                const short* __restrict__ Kip, const short* __restrict__ Vti,
                float* __restrict__ aw_i,
                const short* __restrict__ Keip, const short* __restrict__ Vtei,
                const unsigned* __restrict__ bits_ei,
                short* __restrict__ concat){
  __shared__ short sK[2 * 8192];  // 32 KB
  __shared__ short sV[2 * 8192];  // 32 KB
  __shared__ short sP[8192];      // 16 KB (2 KB per wave)

  const int bid = blockIdx.x;
  const int qt = bid >> 8;               // 0..3
  const int g  = bid & 255;              // b*16+h ; same g -> same XCD
  const int h = g & 15, b = g >> 4;
  const int q0 = qt * 128;
  const int t = threadIdx.x, w = t >> 6, lane = t & 63;
  const int lr = lane & 15, lg = lane >> 4;
  const int qw = q0 + w * 16;
  short* sPw = sP + w * 1024;

  // Q fragments (shared by all three modalities; Q pre-scaled by 0.125)
  const short* Qb = Qp + ((size_t)(b * 512 + qw + lr)) * 1024 + h * 64;
  bf16x8 qf[2];
  qf[0] = *(const bf16x8*)&Qb[lg * 8];
  qf[1] = *(const bf16x8*)&Qb[32 + lg * 8];

  f32x4 tot[4] = {};

  attn_mod<512, true , false>(Kep,  Vte,  bits_e,  aw_e, qf, tot, 1.0f,
                              sK, sV, sPw, b, h, qw, w, lane, lr, lg);
  attn_mod<256, false, false>(Kip,  Vti,  nullptr, aw_i, qf, tot, 0.5f,
                              sK, sV, sPw, b, h, qw, w, lane, lr, lg);
  attn_mod<768, true , true >(Keip, Vtei, bits_ei, nullptr, qf, tot, 0.5f,
                              sK, sV, sPw, b, h, qw, w, lane, lr, lg);

  // epilogue: concat = bf16(tot)
  #pragma unroll
  for (int ni = 0; ni < 4; ++ni)
    #pragma unroll
    for (int j = 0; j < 4; ++j){
      const size_t addr = ((size_t)(b * 512 + qw + lg * 4 + j)) * 1024 + h * 64 + ni * 16 + lr;
      concat[addr] = f2bf(tot[ni][j]);
    }
}

// ---------------------------------------------------------------------------
extern "C" void kernel_launch(void* const* d_in, const int* in_sizes, int n_in,
                              void* d_out, int out_size, void* d_ws, size_t ws_size,
                              hipStream_t stream){
  const float* q    = (const float*)d_in[0];
  const float* k_e  = (const float*)d_in[1];
  const float* v_e  = (const float*)d_in[2];
  const float* k_i  = (const float*)d_in[3];
  const float* v_i  = (const float*)d_in[4];
  const float* k_ei = (const float*)d_in[5];
  const float* v_ei = (const float*)d_in[6];
  const int* mask_e  = (const int*)d_in[7];
  const int* mask_ei = (const int*)d_in[8];
  const int* pad_e   = (const int*)d_in[9];
  const int* pad_ei  = (const int*)d_in[10];
  const float* Wq   = (const float*)d_in[11]; const float* bq   = (const float*)d_in[12];
  const float* Wke  = (const float*)d_in[13]; const float* bke  = (const float*)d_in[14];
  const float* Wve  = (const float*)d_in[15]; const float* bve  = (const float*)d_in[16];
  const float* Wki  = (const float*)d_in[17]; const float* bki  = (const float*)d_in[18];
  const float* Wvi  = (const float*)d_in[19]; const float* bvi  = (const float*)d_in[20];
  const float* Wkei = (const float*)d_in[21]; const float* bkei = (const float*)d_in[22];
  const float* Wvei = (const float*)d_in[23]; const float* bvei = (const float*)d_in[24];
  const float* Wout = (const float*)d_in[25]; const float* bout = (const float*)d_in[26];

  char* ws = (char*)d_ws;
  const size_t MB = 1048576;
  // [0,16)   PW ; [16,64) StA -> Kip[16,24) Vti[24,32) Keip[32,56) bits[56,61)
  // [64,128) StB0/StB1/StC0/StC1 -> concat[64,80)
  // [128,176) Qp/Kep/Vte ; [176,200) Vtei   (200 MB total)
  short* PW   = (short*)(ws);
  short* StA0 = (short*)(ws + 16 * MB);
  short* StA1 = (short*)(ws + 32 * MB);
  short* StA2 = (short*)(ws + 48 * MB);
  short* Kip  = (short*)(ws + 16 * MB);
  short* Vti  = (short*)(ws + 24 * MB);
  short* Keip = (short*)(ws + 32 * MB);
  unsigned* bits_e  = (unsigned*)(ws + 56 * MB);
  unsigned* bits_ei = (unsigned*)(ws + 58 * MB);
  short* StB0 = (short*)(ws + 64 * MB);
  short* StB1 = (short*)(ws + 72 * MB);
  short* StC0 = (short*)(ws + 80 * MB);
  short* StC1 = (short*)(ws + 104 * MB);
  short* concat = (short*)(ws + 64 * MB);
  short* Qp   = (short*)(ws + 128 * MB);
  short* Kep  = (short*)(ws + 144 * MB);
  short* Vte  = (short*)(ws + 160 * MB);
  short* Vtei = (short*)(ws + 176 * MB);

  float* out0 = (float*)d_out;
  float* aw_e = out0 + 8388608;
  float* aw_i = out0 + 75497472;

  // L1: pack weights
  W8 w8;
  w8.w[0] = Wq;  w8.w[1] = Wke;  w8.w[2] = Wve;  w8.w[3] = Wki;
  w8.w[4] = Wvi; w8.w[5] = Wkei; w8.w[6] = Wvei; w8.w[7] = Wout;
  pack_w8<<<dim3(256, 8), 256, 0, stream>>>(w8, PW);

  Big bg{};
  bg.me = mask_e;  bg.pe = pad_e;  bg.be = bits_e;
  bg.mi = mask_ei; bg.pi = pad_ei; bg.bi = bits_ei;

  // L2: cvt A (q, k_e, v_e -> StA)
  {
    Big c = bg;
    c.cin[0] = q;   c.cout[0] = StA0; c.n8[0] = 1048576;
    c.cin[1] = k_e; c.cout[1] = StA1; c.n8[1] = 1048576;
    c.cin[2] = v_e; c.cout[2] = StA2; c.n8[2] = 1048576;
    c.act[0] = 4; c.act[1] = 5; c.act[2] = 6;
    mixk<<<dim3(96, 4, 3), 256, 0, stream>>>(c);
  }
  // L3: gemm A (z0-2, n-paired y=4)  ||  cvt B/C (z3-6)
  {
    Big c = bg;
    c.g[0] = {StA0, PW + 0 * 1048576, bq,  Qp,  0, 512, 64, 0.125f};
    c.g[1] = {StA1, PW + 1 * 1048576, bke, Kep, 0, 512, 64, 1.0f};
    c.g[2] = {StA2, PW + 2 * 1048576, bve, Vte, 1, 512, 64, 1.0f};
    c.cin[0] = k_i;  c.cout[0] = StB0; c.n8[0] = 524288;
    c.cin[1] = v_i;  c.cout[1] = StB1; c.n8[1] = 524288;
    c.cin[2] = k_ei; c.cout[2] = StC0; c.n8[2] = 1572864;
    c.cin[3] = v_ei; c.cout[3] = StC1; c.n8[3] = 1572864;
    c.act[0] = 0; c.act[1] = 1; c.act[2] = 2;
    c.act[3] = 4; c.act[4] = 5; c.act[5] = 6; c.act[6] = 7;
    mixk<<<dim3(96, 4, 7), 256, 0, stream>>>(c);
  }
  // L4: gemm B/C (z0-3, n-paired y=4)  ||  bits (z4-5)
  {
    Big c = bg;
    c.g[0] = {StB0, PW + 3 * 1048576, bki,  Kip,  0, 256, 32, 1.0f};
    c.g[1] = {StB1, PW + 4 * 1048576, bvi,  Vti,  1, 256, 32, 1.0f};
    c.g[2] = {StC0, PW + 5 * 1048576, bkei, Keip, 0, 768, 96, 1.0f};
    c.g[3] = {StC1, PW + 6 * 1048576, bvei, Vtei, 1, 768, 96, 1.0f};
    c.act[0] = 0; c.act[1] = 1; c.act[2] = 2; c.act[3] = 3;
    c.act[4] = 8; c.act[5] = 9;
    mixk<<<dim3(96, 4, 6), 256, 0, stream>>>(c);
  }

  // L5: fused attention
  attn_fused<<<1024, 512, 0, stream>>>(Qp, Kep, Vte, bits_e, aw_e,
                                       Kip, Vti, aw_i, Keip, Vtei, bits_ei, concat);

  // L6: output GEMM (n-paired)
  {
    Big c = bg;
    c.g[0] = {concat, PW + 7 * 1048576, bout, out0, 2, 512, 64, 1.0f};
    c.act[0] = 0;
    mixk<<<dim3(64, 4, 1), 256, 0, stream>>>(c);
  }
}

// Round 19
// 523.508 us; speedup vs baseline: 1.2888x; 1.2888x over previous
//
#include <hip/hip_runtime.h>
#include <stdint.h>

typedef __attribute__((ext_vector_type(8))) short bf16x8;
typedef __attribute__((ext_vector_type(4))) short s16x4;
typedef __attribute__((ext_vector_type(4))) float f32x4;

__device__ __forceinline__ short f2bf(float f){
  unsigned x = __float_as_uint(f);
  unsigned r = (x + 0x7fffu + ((x >> 16) & 1u)) >> 16;
  return (short)r;
}

// async global->LDS, 16B per lane (dest = wave-uniform base + lane*16)
__device__ __forceinline__ void g2l16(const void* g, void* l){
  __builtin_amdgcn_global_load_lds(
      (const __attribute__((address_space(1))) unsigned int*)(unsigned long long)(uintptr_t)g,
      (__attribute__((address_space(3))) unsigned int*)(unsigned int)(uintptr_t)l,
      16, 0, 0);
}

// ---------------------------------------------------------------------------
// Pack 8 weights (f32, 1024x1024 row-major K x N) into bf16 tiles.
// W0 (Wq) pre-scaled by 1/sqrt(DK)=0.125 (exact pow2 -> same bf16 rounding).
// ---------------------------------------------------------------------------
struct W8 { const float* w[8]; };
__global__ __launch_bounds__(256) void pack_w8(W8 ws8, short* __restrict__ out){
  const int m = blockIdx.y;
  const float scl = (m == 0) ? 0.125f : 1.0f;
  const float* __restrict__ W = ws8.w[m];
  short* o = out + (size_t)m * 1048576 + (size_t)blockIdx.x * 4096;
  const int kt = blockIdx.x & 31, nt = blockIdx.x >> 5;
  const int t = threadIdx.x;
  #pragma unroll
  for (int i = 0; i < 16; ++i){
    int flat = i * 256 + t;              // 0..4095
    int kl = flat >> 7;                  // /128
    int nl = flat & 127;
    o[nl * 32 + kl] = f2bf(W[(size_t)(kt * 32 + kl) * 1024 + nt * 128 + nl] * scl);
  }
}

// ---------------------------------------------------------------------------
// Heterogeneous batched kernel: per-z action
//   act 0..3  : GEMM segment (128x128 tile, BK=32, dbuf 2-phase, R7-verified;
//               no setprio -- lockstep GEMM is the m190 regime where it hurts)
//   act 4..7  : f32->bf16 convert segment (grid-stride)
//   act 8 / 9 : mask||pad -> bitmask (e / ei)
// GEMM om: 0 = C bf16 row-major, 1 = C bf16 as (B,H=16,DK=64,S), 2 = C f32.
// ---------------------------------------------------------------------------
struct GSeg { const short* A; const short* Wp; const float* bias; void* C;
              int om; int S; int mt; float bs; };
struct Big {
  GSeg g[4];
  const float* cin[4]; short* cout[4]; int n8[4];
  const int* me; const int* pe; unsigned* be;
  const int* mi; const int* pi; unsigned* bi;
  int act[8];
};

__device__ __forceinline__ void gemm_core(const GSeg sg,
                                          short (*sA)[4096], short (*sB)[4096]){
  if ((int)blockIdx.x >= sg.mt) return;
  const int t = threadIdx.x;
  const int m0 = blockIdx.x * 128;
  const int nt = blockIdx.y;             // 0..7
  const int n0 = nt * 128;
  const int w = t >> 6, lane = t & 63, lr = lane & 15, lg = lane >> 4;
  const int wm = (w >> 1) * 64, wn = (w & 1) * 64;

  const int arow  = t >> 2;
  const int acol8 = (t & 3) * 8;
  const short* Ag = sg.A + (size_t)(m0 + arow) * 1024 + acol8;
  const short* Bg = sg.Wp + (size_t)nt * 32 * 4096 + t * 8;

  f32x4 acc[4][4] = {};

  // prologue: stage tile 0 into buffer 0
  g2l16(Ag, sA[0] + t * 8);
  g2l16(Ag + 64 * 1024, sA[0] + 2048 + t * 8);
  g2l16(Bg, sB[0] + t * 8);
  g2l16(Bg + 2048, sB[0] + 2048 + t * 8);

  int cur = 0;
  for (int kt = 0; kt < 32; ++kt){
    __syncthreads();                     // drains vmcnt -> buf[cur] ready
    if (kt < 31){                        // issue next tile into buf[cur^1]
      const int kn = kt + 1;
      g2l16(Ag + kn * 32, sA[cur ^ 1] + t * 8);
      g2l16(Ag + 64 * 1024 + kn * 32, sA[cur ^ 1] + 2048 + t * 8);
      const short* bt = Bg + (size_t)kn * 4096;
      g2l16(bt, sB[cur ^ 1] + t * 8);
      g2l16(bt + 2048, sB[cur ^ 1] + 2048 + t * 8);
    }

    bf16x8 af[4], bfr[4];
    #pragma unroll
    for (int mi = 0; mi < 4; ++mi)
      af[mi] = *(const bf16x8*)&sA[cur][(wm + mi * 16 + lr) * 32 + lg * 8];
    #pragma unroll
    for (int ni = 0; ni < 4; ++ni)
      bfr[ni] = *(const bf16x8*)&sB[cur][(wn + ni * 16 + lr) * 32 + lg * 8];
    #pragma unroll
    for (int mi = 0; mi < 4; ++mi)
      #pragma unroll
      for (int ni = 0; ni < 4; ++ni)
        acc[mi][ni] = __builtin_amdgcn_mfma_f32_16x16x32_bf16(
            af[mi], bfr[ni], acc[mi][ni], 0, 0, 0);
    cur ^= 1;
  }

  #pragma unroll
  for (int ni = 0; ni < 4; ++ni){
    const int n = n0 + wn + ni * 16 + lr;
    const float bv = sg.bias[n] * sg.bs;
    #pragma unroll
    for (int mi = 0; mi < 4; ++mi){
      const int mb = m0 + wm + mi * 16 + lg * 4;
      if (sg.om == 0){
        short* C = (short*)sg.C;
        #pragma unroll
        for (int j = 0; j < 4; ++j)
          C[(size_t)(mb + j) * 1024 + n] = f2bf(acc[mi][ni][j] + bv);
      } else if (sg.om == 1){
        short* C = (short*)sg.C;
        const int bb = mb / sg.S, sb = mb % sg.S;
        const int hh = n >> 6, dk = n & 63;
        s16x4 pk;
        #pragma unroll
        for (int j = 0; j < 4; ++j) pk[j] = f2bf(acc[mi][ni][j] + bv);
        *(s16x4*)&C[(((size_t)bb * 16 + hh) * 64 + dk) * sg.S + sb] = pk;
      } else {
        float* C = (float*)sg.C;
        #pragma unroll
        for (int j = 0; j < 4; ++j)
          C[(size_t)(mb + j) * 1024 + n] = acc[mi][ni][j] + bv;
      }
    }
  }
}

__device__ __forceinline__ void cvt_core(const float* __restrict__ in,
                                         short* __restrict__ out, int n8){
  const long long total = (long long)gridDim.x * gridDim.y * 256;
  for (long long i = (long long)(blockIdx.y * gridDim.x + blockIdx.x) * 256 + threadIdx.x;
       i < n8; i += total){
    const float4* p = (const float4*)in + i * 2;
    const float4 a = p[0], b = p[1];
    bf16x8 v;
    v[0] = f2bf(a.x); v[1] = f2bf(a.y); v[2] = f2bf(a.z); v[3] = f2bf(a.w);
    v[4] = f2bf(b.x); v[5] = f2bf(b.y); v[6] = f2bf(b.z); v[7] = f2bf(b.w);
    *(bf16x8*)(out + i * 8) = v;
  }
}

__device__ __forceinline__ void bits_core(const int* __restrict__ mask,
                                          const int* __restrict__ pad,
                                          unsigned* __restrict__ bits,
                                          int SK, int nsb, int nunits){
  const int nb = gridDim.x * gridDim.y;
  for (int u = blockIdx.y * gridDim.x + blockIdx.x; u < nunits; u += nb){
    const int row = u / nsb, sb = u - row * nsb;   // row = b*512+q
    const int s = sb * 256 + threadIdx.x;
    const int b = row >> 9;
    const bool v = (mask[(size_t)row * SK + s] != 0) || (pad[(size_t)b * SK + s] != 0);
    unsigned long long bal = __ballot(v);
    const int lane = threadIdx.x & 63;
    if ((lane & 31) == 0)
      bits[((size_t)row * SK + s) >> 5] = (unsigned)(bal >> (lane & 32));
  }
}

__global__ __launch_bounds__(256) void mixk(Big big){
  __shared__ short sA[2][4096];
  __shared__ short sB[2][4096];
  const int a = big.act[blockIdx.z];
  if (a < 4)       gemm_core(big.g[a], sA, sB);
  else if (a < 8)  cvt_core(big.cin[a - 4], big.cout[a - 4], big.n8[a - 4]);
  else if (a == 8) bits_core(big.me, big.pe, big.be, 512, 2, 16384);
  else             bits_core(big.mi, big.pi, big.bi, 768, 3, 24576);
}

// ---------------------------------------------------------------------------
// One attention modality (8-wave block, 128 q-rows), accumulating wgt*O into
// tot. K/V staging double-buffered (R14-verified; NO setprio -- lockstep
// 8-wave blocks are the m190 regime where it hurts). Even NT => phase
// prologues target buf0 with no cross-phase WAR.
// No-max softmax (Q pre-scaled by 0.125; masked -1e30 -> exp == 0; l==0
// guarded). aw stores nontemporal.
// SINGLE=false: two-phase (P1: l only; P2: recompute + aw + PV). aw written.
// SINGLE=true : single-pass, no aw, unnormalized PV, normalize at end.
// ---------------------------------------------------------------------------
template<int SK, bool HAS_BIAS, bool SINGLE>
__device__ __forceinline__ void attn_mod(
    const short* __restrict__ Kp, const short* __restrict__ Vt,
    const unsigned* __restrict__ bits, float* __restrict__ aw,
    const bf16x8 (&qf)[2], f32x4 (&tot)[4], float wgt,
    short* sK, short* sV, short* sPw,
    int b, int h, int qw, int w, int lane, int lr, int lg){
  constexpr int NT  = SK / 128;
  constexpr int SKW = SK / 32;
  static_assert((NT & 1) == 0, "buffer-parity argument needs even NT");

  const int kchunk = (lane & 7) ^ ((lane >> 3) & 7);
  const short* Ksrc = Kp + ((size_t)b * SK + w * 16 + (lane >> 3)) * 1024 + h * 64 + kchunk * 8;
  const short* Vsrc = Vt + ((size_t)(b * 16 + h)) * 64 * SK;
  const int ldoff = w * 1024 + lane * 8;

  const unsigned* bitrow[4];
  if (HAS_BIAS){
    #pragma unroll
    for (int j = 0; j < 4; ++j)
      bitrow[j] = bits + ((size_t)(b * 512 + qw + lg * 4 + j)) * SKW;
  }

  float lrow[4];
  #pragma unroll
  for (int j = 0; j < 4; ++j) lrow[j] = 0.f;
  f32x4 acco[4] = {};

#define SKB(c) (sK + (c) * 8192)
#define SVB(c) (sV + (c) * 8192)
#define STAGE_K(c, s0) do{ \
    g2l16(Ksrc + (size_t)(s0) * 1024, SKB(c) + ldoff); \
    g2l16(Ksrc + (size_t)((s0) + 8) * 1024, SKB(c) + ldoff + 512); }while(0)
#define STAGE_V(c, s0) do{ \
    const int dd0 = w * 8 + (lane >> 4); \
    const int cg0 = (lane & 15) ^ (dd0 & 15); \
    g2l16(Vsrc + (size_t)dd0 * SK + (s0) + cg0 * 8, SVB(c) + ldoff); \
    const int dd1 = dd0 + 4; \
    const int cg1 = (lane & 15) ^ (dd1 & 15); \
    g2l16(Vsrc + (size_t)dd1 * SK + (s0) + cg1 * 8, SVB(c) + ldoff + 512); }while(0)

  if (!SINGLE){
    // ---------------- Phase 1: row-sum l only (K dbuf) ----------------
    STAGE_K(0, 0);
    int cur = 0;
    for (int tt = 0; tt < NT; ++tt){
      __syncthreads();                    // buf[cur] ready
      if (tt + 1 < NT) STAGE_K(cur ^ 1, (tt + 1) * 128);
      const short* kb = SKB(cur);

      f32x4 accs[8];
      #pragma unroll
      for (int si = 0; si < 8; ++si){
        f32x4 a = {};
        #pragma unroll
        for (int dt = 0; dt < 2; ++dt){
          bf16x8 kf = *(const bf16x8*)&kb[(si * 16 + lr) * 64 + ((dt * 4 + lg) ^ (lr & 7)) * 8];
          a = __builtin_amdgcn_mfma_f32_16x16x32_bf16(qf[dt], kf, a, 0, 0, 0);
        }
        accs[si] = a;
      }

      #pragma unroll
      for (int j = 0; j < 4; ++j){
        unsigned wb[4];
        if (HAS_BIAS){
          #pragma unroll
          for (int sp = 0; sp < 4; ++sp) wb[sp] = bitrow[j][tt * 4 + sp];
        }
        float ssum = 0.f;
        #pragma unroll
        for (int si = 0; si < 8; ++si){
          float v = accs[si][j];
          if (HAS_BIAS && ((wb[si >> 1] >> ((si & 1) * 16 + lr)) & 1u)) v = -1e30f;
          ssum += __expf(v);
        }
        lrow[j] += ssum;
      }
      cur ^= 1;
    }

    // merge l across the 16 lr lanes
    #pragma unroll
    for (int j = 0; j < 4; ++j){
      #pragma unroll
      for (int d = 1; d < 16; d <<= 1) lrow[j] += __shfl_xor(lrow[j], d);
    }
    float rinv[4];
    #pragma unroll
    for (int j = 0; j < 4; ++j) rinv[j] = lrow[j] > 0.f ? 1.0f / lrow[j] : 0.f;

    // ---------------- Phase 2: aw + PV (K+V dbuf) ----------------
    STAGE_K(0, 0);
    STAGE_V(0, 0);
    cur = 0;
    for (int tt = 0; tt < NT; ++tt){
      const int s0 = tt * 128;
      __syncthreads();
      if (tt + 1 < NT){ STAGE_K(cur ^ 1, s0 + 128); STAGE_V(cur ^ 1, s0 + 128); }
      const short* kb = SKB(cur);
      const short* vb = SVB(cur);

      f32x4 accs[8];
      #pragma unroll
      for (int si = 0; si < 8; ++si){
        f32x4 a = {};
        #pragma unroll
        for (int dt = 0; dt < 2; ++dt){
          bf16x8 kf = *(const bf16x8*)&kb[(si * 16 + lr) * 64 + ((dt * 4 + lg) ^ (lr & 7)) * 8];
          a = __builtin_amdgcn_mfma_f32_16x16x32_bf16(qf[dt], kf, a, 0, 0, 0);
        }
        accs[si] = a;
      }

      #pragma unroll
      for (int half = 0; half < 2; ++half){
        #pragma unroll
        for (int j = 0; j < 4; ++j){
          unsigned wb[2];
          if (HAS_BIAS){
            #pragma unroll
            for (int sp = 0; sp < 2; ++sp) wb[sp] = bitrow[j][tt * 4 + half * 2 + sp];
          }
          const int qq = lg * 4 + j;
          float* awrow = aw + (((size_t)(b * 16 + h)) * 512 + qw + qq) * SK + s0 + half * 64 + lr;
          #pragma unroll
          for (int si2 = 0; si2 < 4; ++si2){
            const int si = half * 4 + si2;
            float v = accs[si][j];
            if (HAS_BIAS && ((wb[si2 >> 1] >> ((si2 & 1) * 16 + lr)) & 1u)) v = -1e30f;
            const float p = __expf(v) * rinv[j];
            __builtin_nontemporal_store(p, &awrow[si2 * 16]);
            sPw[qq * 64 + (((si2 * 2 + (lr >> 3)) ^ (qq & 7)) * 8) + (lr & 7)] = f2bf(p);
          }
        }
        // PV half (same-wave LDS write->read; DS ops are in-order)
        #pragma unroll
        for (int kt2 = 0; kt2 < 2; ++kt2){
          const int kt = half * 2 + kt2;
          bf16x8 pa = *(const bf16x8*)&sPw[lr * 64 + (((kt2 * 4 + lg) ^ (lr & 7)) * 8)];
          #pragma unroll
          for (int ni = 0; ni < 4; ++ni){
            bf16x8 vf = *(const bf16x8*)&vb[(ni * 16 + lr) * 128 + ((kt * 4 + lg) ^ lr) * 8];
            acco[ni] = __builtin_amdgcn_mfma_f32_16x16x32_bf16(pa, vf, acco[ni], 0, 0, 0);
          }
        }
      }
      cur ^= 1;
    }

    #pragma unroll
    for (int ni = 0; ni < 4; ++ni)
      #pragma unroll
      for (int j = 0; j < 4; ++j)
        tot[ni][j] += wgt * acco[ni][j];
  } else {
    // ---------------- single-pass, unnormalized PV (K+V dbuf) ----------------
    STAGE_K(0, 0);
    STAGE_V(0, 0);
    int cur = 0;
    for (int tt = 0; tt < NT; ++tt){
      const int s0 = tt * 128;
      __syncthreads();
      if (tt + 1 < NT){ STAGE_K(cur ^ 1, s0 + 128); STAGE_V(cur ^ 1, s0 + 128); }
      const short* kb = SKB(cur);
      const short* vb = SVB(cur);

      f32x4 accs[8];
      #pragma unroll
      for (int si = 0; si < 8; ++si){
        f32x4 a = {};
        #pragma unroll
        for (int dt = 0; dt < 2; ++dt){
          bf16x8 kf = *(const bf16x8*)&kb[(si * 16 + lr) * 64 + ((dt * 4 + lg) ^ (lr & 7)) * 8];
          a = __builtin_amdgcn_mfma_f32_16x16x32_bf16(qf[dt], kf, a, 0, 0, 0);
        }
        accs[si] = a;
      }

      #pragma unroll
      for (int half = 0; half < 2; ++half){
        #pragma unroll
        for (int j = 0; j < 4; ++j){
          unsigned wb[2];
          if (HAS_BIAS){
            #pragma unroll
            for (int sp = 0; sp < 2; ++sp) wb[sp] = bitrow[j][tt * 4 + half * 2 + sp];
          }
          const int qq = lg * 4 + j;
          float ls = 0.f;
          #pragma unroll
          for (int si2 = 0; si2 < 4; ++si2){
            const int si = half * 4 + si2;
            float v = accs[si][j];
            if (HAS_BIAS && ((wb[si2 >> 1] >> ((si2 & 1) * 16 + lr)) & 1u)) v = -1e30f;
            const float p = __expf(v);
            ls += p;
            sPw[qq * 64 + (((si2 * 2 + (lr >> 3)) ^ (qq & 7)) * 8) + (lr & 7)] = f2bf(p);
          }
          lrow[j] += ls;
        }
        #pragma unroll
        for (int kt2 = 0; kt2 < 2; ++kt2){
          const int kt = half * 2 + kt2;
          bf16x8 pa = *(const bf16x8*)&sPw[lr * 64 + (((kt2 * 4 + lg) ^ (lr & 7)) * 8)];
          #pragma unroll
          for (int ni = 0; ni < 4; ++ni){
            bf16x8 vf = *(const bf16x8*)&vb[(ni * 16 + lr) * 128 + ((kt * 4 + lg) ^ lr) * 8];
            acco[ni] = __builtin_amdgcn_mfma_f32_16x16x32_bf16(pa, vf, acco[ni], 0, 0, 0);
          }
        }
      }
      cur ^= 1;
    }

    // final normalize
    #pragma unroll
    for (int j = 0; j < 4; ++j){
      #pragma unroll
      for (int d = 1; d < 16; d <<= 1) lrow[j] += __shfl_xor(lrow[j], d);
      const float r = lrow[j] > 0.f ? wgt / lrow[j] : 0.f;
      #pragma unroll
      for (int ni = 0; ni < 4; ++ni) tot[ni][j] += r * acco[ni][j];
    }
  }
#undef SKB
#undef SVB
#undef STAGE_K
#undef STAGE_V
}

// ---------------------------------------------------------------------------
// Fused attention: all three modalities per block; concat written directly.
// Block = (b, h, 128 q-rows), 8 waves, 512 threads, 80 KB LDS (2 blocks/CU).
// XCD-aware bid decode: same-(b,h) blocks differ by 256 (= 0 mod 8).
// ---------------------------------------------------------------------------
__global__ __launch_bounds__(512)
void attn_fused(const short* __restrict__ Qp,
                const short* __restrict__ Kep, const short* __restrict__ Vte,
                const unsigned* __restrict__ bits_e, float* __restrict__ aw_e,
                const short* __restrict__ Kip, const short* __restrict__ Vti,
                float* __restrict__ aw_i,
                const short* __restrict__ Keip, const short* __restrict__ Vtei,
                const unsigned* __restrict__ bits_ei,
                short* __restrict__ concat){
  __shared__ short sK[2 * 8192];  // 32 KB
  __shared__ short sV[2 * 8192];  // 32 KB
  __shared__ short sP[8192];      // 16 KB (2 KB per wave)

  const int bid = blockIdx.x;
  const int qt = bid >> 8;               // 0..3
  const int g  = bid & 255;              // b*16+h ; same g -> same XCD
  const int h = g & 15, b = g >> 4;
  const int q0 = qt * 128;
  const int t = threadIdx.x, w = t >> 6, lane = t & 63;
  const int lr = lane & 15, lg = lane >> 4;
  const int qw = q0 + w * 16;
  short* sPw = sP + w * 1024;

  // Q fragments (shared by all three modalities; Q pre-scaled by 0.125)
  const short* Qb = Qp + ((size_t)(b * 512 + qw + lr)) * 1024 + h * 64;
  bf16x8 qf[2];
  qf[0] = *(const bf16x8*)&Qb[lg * 8];
  qf[1] = *(const bf16x8*)&Qb[32 + lg * 8];

  f32x4 tot[4] = {};

  attn_mod<512, true , false>(Kep,  Vte,  bits_e,  aw_e, qf, tot, 1.0f,
                              sK, sV, sPw, b, h, qw, w, lane, lr, lg);
  attn_mod<256, false, false>(Kip,  Vti,  nullptr, aw_i, qf, tot, 0.5f,
                              sK, sV, sPw, b, h, qw, w, lane, lr, lg);
  attn_mod<768, true , true >(Keip, Vtei, bits_ei, nullptr, qf, tot, 0.5f,
                              sK, sV, sPw, b, h, qw, w, lane, lr, lg);

  // epilogue: concat = bf16(tot)
  #pragma unroll
  for (int ni = 0; ni < 4; ++ni)
    #pragma unroll
    for (int j = 0; j < 4; ++j){
      const size_t addr = ((size_t)(b * 512 + qw + lg * 4 + j)) * 1024 + h * 64 + ni * 16 + lr;
      concat[addr] = f2bf(tot[ni][j]);
    }
}

// ---------------------------------------------------------------------------
extern "C" void kernel_launch(void* const* d_in, const int* in_sizes, int n_in,
                              void* d_out, int out_size, void* d_ws, size_t ws_size,
                              hipStream_t stream){
  const float* q    = (const float*)d_in[0];
  const float* k_e  = (const float*)d_in[1];
  const float* v_e  = (const float*)d_in[2];
  const float* k_i  = (const float*)d_in[3];
  const float* v_i  = (const float*)d_in[4];
  const float* k_ei = (const float*)d_in[5];
  const float* v_ei = (const float*)d_in[6];
  const int* mask_e  = (const int*)d_in[7];
  const int* mask_ei = (const int*)d_in[8];
  const int* pad_e   = (const int*)d_in[9];
  const int* pad_ei  = (const int*)d_in[10];
  const float* Wq   = (const float*)d_in[11]; const float* bq   = (const float*)d_in[12];
  const float* Wke  = (const float*)d_in[13]; const float* bke  = (const float*)d_in[14];
  const float* Wve  = (const float*)d_in[15]; const float* bve  = (const float*)d_in[16];
  const float* Wki  = (const float*)d_in[17]; const float* bki  = (const float*)d_in[18];
  const float* Wvi  = (const float*)d_in[19]; const float* bvi  = (const float*)d_in[20];
  const float* Wkei = (const float*)d_in[21]; const float* bkei = (const float*)d_in[22];
  const float* Wvei = (const float*)d_in[23]; const float* bvei = (const float*)d_in[24];
  const float* Wout = (const float*)d_in[25]; const float* bout = (const float*)d_in[26];

  char* ws = (char*)d_ws;
  const size_t MB = 1048576;
  // [0,16)   PW ; [16,64) StA -> Kip[16,24) Vti[24,32) Keip[32,56) bits[56,61)
  // [64,128) StB0/StB1/StC0/StC1 -> concat[64,80)
  // [128,176) Qp/Kep/Vte ; [176,200) Vtei   (200 MB total)
  short* PW   = (short*)(ws);
  short* StA0 = (short*)(ws + 16 * MB);
  short* StA1 = (short*)(ws + 32 * MB);
  short* StA2 = (short*)(ws + 48 * MB);
  short* Kip  = (short*)(ws + 16 * MB);
  short* Vti  = (short*)(ws + 24 * MB);
  short* Keip = (short*)(ws + 32 * MB);
  unsigned* bits_e  = (unsigned*)(ws + 56 * MB);
  unsigned* bits_ei = (unsigned*)(ws + 58 * MB);
  short* StB0 = (short*)(ws + 64 * MB);
  short* StB1 = (short*)(ws + 72 * MB);
  short* StC0 = (short*)(ws + 80 * MB);
  short* StC1 = (short*)(ws + 104 * MB);
  short* concat = (short*)(ws + 64 * MB);
  short* Qp   = (short*)(ws + 128 * MB);
  short* Kep  = (short*)(ws + 144 * MB);
  short* Vte  = (short*)(ws + 160 * MB);
  short* Vtei = (short*)(ws + 176 * MB);

  float* out0 = (float*)d_out;
  float* aw_e = out0 + 8388608;
  float* aw_i = out0 + 75497472;

  // L1: pack weights
  W8 w8;
  w8.w[0] = Wq;  w8.w[1] = Wke;  w8.w[2] = Wve;  w8.w[3] = Wki;
  w8.w[4] = Wvi; w8.w[5] = Wkei; w8.w[6] = Wvei; w8.w[7] = Wout;
  pack_w8<<<dim3(256, 8), 256, 0, stream>>>(w8, PW);

  Big bg{};
  bg.me = mask_e;  bg.pe = pad_e;  bg.be = bits_e;
  bg.mi = mask_ei; bg.pi = pad_ei; bg.bi = bits_ei;

  // L2: cvt A (q, k_e, v_e -> StA)
  {
    Big c = bg;
    c.cin[0] = q;   c.cout[0] = StA0; c.n8[0] = 1048576;
    c.cin[1] = k_e; c.cout[1] = StA1; c.n8[1] = 1048576;
    c.cin[2] = v_e; c.cout[2] = StA2; c.n8[2] = 1048576;
    c.act[0] = 4; c.act[1] = 5; c.act[2] = 6;
    mixk<<<dim3(96, 8, 3), 256, 0, stream>>>(c);
  }
  // L3: gemm A (z0-2)  ||  cvt B/C (z3-6)
  {
    Big c = bg;
    c.g[0] = {StA0, PW + 0 * 1048576, bq,  Qp,  0, 512, 64, 0.125f};
    c.g[1] = {StA1, PW + 1 * 1048576, bke, Kep, 0, 512, 64, 1.0f};
    c.g[2] = {StA2, PW + 2 * 1048576, bve, Vte, 1, 512, 64, 1.0f};
    c.cin[0] = k_i;  c.cout[0] = StB0; c.n8[0] = 524288;
    c.cin[1] = v_i;  c.cout[1] = StB1; c.n8[1] = 524288;
    c.cin[2] = k_ei; c.cout[2] = StC0; c.n8[2] = 1572864;
    c.cin[3] = v_ei; c.cout[3] = StC1; c.n8[3] = 1572864;
    c.act[0] = 0; c.act[1] = 1; c.act[2] = 2;
    c.act[3] = 4; c.act[4] = 5; c.act[5] = 6; c.act[6] = 7;
    mixk<<<dim3(96, 8, 7), 256, 0, stream>>>(c);
  }
  // L4: gemm B/C (z0-3)  ||  bits (z4-5)
  {
    Big c = bg;
    c.g[0] = {StB0, PW + 3 * 1048576, bki,  Kip,  0, 256, 32, 1.0f};
    c.g[1] = {StB1, PW + 4 * 1048576, bvi,  Vti,  1, 256, 32, 1.0f};
    c.g[2] = {StC0, PW + 5 * 1048576, bkei, Keip, 0, 768, 96, 1.0f};
    c.g[3] = {StC1, PW + 6 * 1048576, bvei, Vtei, 1, 768, 96, 1.0f};
    c.act[0] = 0; c.act[1] = 1; c.act[2] = 2; c.act[3] = 3;
    c.act[4] = 8; c.act[5] = 9;
    mixk<<<dim3(96, 8, 6), 256, 0, stream>>>(c);
  }

  // L5: fused attention
  attn_fused<<<1024, 512, 0, stream>>>(Qp, Kep, Vte, bits_e, aw_e,
                                       Kip, Vti, aw_i, Keip, Vtei, bits_ei, concat);

  // L6: output GEMM
  {
    Big c = bg;
    c.g[0] = {concat, PW + 7 * 1048576, bout, out0, 2, 512, 64, 1.0f};
    c.act[0] = 0;
    mixk<<<dim3(64, 8, 1), 256, 0, stream>>>(c);
  }
}

// Round 20
// 520.544 us; speedup vs baseline: 1.2961x; 1.0057x over previous
//
#include <hip/hip_runtime.h>
#include <stdint.h>

typedef __attribute__((ext_vector_type(8))) short bf16x8;
typedef __attribute__((ext_vector_type(4))) short s16x4;
typedef __attribute__((ext_vector_type(4))) float f32x4;

__device__ __forceinline__ short f2bf(float f){
  unsigned x = __float_as_uint(f);
  unsigned r = (x + 0x7fffu + ((x >> 16) & 1u)) >> 16;
  return (short)r;
}

// async global->LDS, 16B per lane (dest = wave-uniform base + lane*16)
__device__ __forceinline__ void g2l16(const void* g, void* l){
  __builtin_amdgcn_global_load_lds(
      (const __attribute__((address_space(1))) unsigned int*)(unsigned long long)(uintptr_t)g,
      (__attribute__((address_space(3))) unsigned int*)(unsigned int)(uintptr_t)l,
      16, 0, 0);
}

// ---------------------------------------------------------------------------
// Heterogeneous batched kernel: per-z action
//   act 0..3  : GEMM segment (128x128 tile, BK=32, dbuf 2-phase, R7-verified;
//               no setprio -- lockstep GEMM is the m190 regime where it hurts)
//   act 4..7  : f32->bf16 convert segment (grid-stride)
//   act 8 / 9 : mask||pad -> bitmask (e / ei)
//   act 10    : pack 8 weights into bf16 tiles (x=tile 0..255, y=weight 0..7;
//               W0 pre-scaled by 1/sqrt(DK)=0.125, exact pow2)
// GEMM om: 0 = C bf16 row-major, 1 = C bf16 as (B,H=16,DK=64,S), 2 = C f32.
// ---------------------------------------------------------------------------
struct GSeg { const short* A; const short* Wp; const float* bias; void* C;
              int om; int S; int mt; float bs; };
struct Big {
  GSeg g[4];
  const float* cin[4]; short* cout[4]; int n8[4];
  const int* me; const int* pe; unsigned* be;
  const int* mi; const int* pi; unsigned* bi;
  const float* wsrc[8]; short* pwout;
  int act[8];
};

__device__ __forceinline__ void pack_core(const Big& big){
  const int m = blockIdx.y;
  const float scl = (m == 0) ? 0.125f : 1.0f;
  const float* __restrict__ W = big.wsrc[m];
  short* o = big.pwout + (size_t)m * 1048576 + (size_t)blockIdx.x * 4096;
  const int kt = blockIdx.x & 31, nt = blockIdx.x >> 5;
  const int t = threadIdx.x;
  #pragma unroll
  for (int i = 0; i < 16; ++i){
    int flat = i * 256 + t;              // 0..4095
    int kl = flat >> 7;                  // /128
    int nl = flat & 127;
    o[nl * 32 + kl] = f2bf(W[(size_t)(kt * 32 + kl) * 1024 + nt * 128 + nl] * scl);
  }
}

__device__ __forceinline__ void gemm_core(const GSeg sg,
                                          short (*sA)[4096], short (*sB)[4096]){
  if ((int)blockIdx.x >= sg.mt) return;
  const int t = threadIdx.x;
  const int m0 = blockIdx.x * 128;
  const int nt = blockIdx.y;             // 0..7
  const int n0 = nt * 128;
  const int w = t >> 6, lane = t & 63, lr = lane & 15, lg = lane >> 4;
  const int wm = (w >> 1) * 64, wn = (w & 1) * 64;

  const int arow  = t >> 2;
  const int acol8 = (t & 3) * 8;
  const short* Ag = sg.A + (size_t)(m0 + arow) * 1024 + acol8;
  const short* Bg = sg.Wp + (size_t)nt * 32 * 4096 + t * 8;

  f32x4 acc[4][4] = {};

  // prologue: stage tile 0 into buffer 0
  g2l16(Ag, sA[0] + t * 8);
  g2l16(Ag + 64 * 1024, sA[0] + 2048 + t * 8);
  g2l16(Bg, sB[0] + t * 8);
  g2l16(Bg + 2048, sB[0] + 2048 + t * 8);

  int cur = 0;
  for (int kt = 0; kt < 32; ++kt){
    __syncthreads();                     // drains vmcnt -> buf[cur] ready
    if (kt < 31){                        // issue next tile into buf[cur^1]
      const int kn = kt + 1;
      g2l16(Ag + kn * 32, sA[cur ^ 1] + t * 8);
      g2l16(Ag + 64 * 1024 + kn * 32, sA[cur ^ 1] + 2048 + t * 8);
      const short* bt = Bg + (size_t)kn * 4096;
      g2l16(bt, sB[cur ^ 1] + t * 8);
      g2l16(bt + 2048, sB[cur ^ 1] + 2048 + t * 8);
    }

    bf16x8 af[4], bfr[4];
    #pragma unroll
    for (int mi = 0; mi < 4; ++mi)
      af[mi] = *(const bf16x8*)&sA[cur][(wm + mi * 16 + lr) * 32 + lg * 8];
    #pragma unroll
    for (int ni = 0; ni < 4; ++ni)
      bfr[ni] = *(const bf16x8*)&sB[cur][(wn + ni * 16 + lr) * 32 + lg * 8];
    #pragma unroll
    for (int mi = 0; mi < 4; ++mi)
      #pragma unroll
      for (int ni = 0; ni < 4; ++ni)
        acc[mi][ni] = __builtin_amdgcn_mfma_f32_16x16x32_bf16(
            af[mi], bfr[ni], acc[mi][ni], 0, 0, 0);
    cur ^= 1;
  }

  #pragma unroll
  for (int ni = 0; ni < 4; ++ni){
    const int n = n0 + wn + ni * 16 + lr;
    const float bv = sg.bias[n] * sg.bs;
    #pragma unroll
    for (int mi = 0; mi < 4; ++mi){
      const int mb = m0 + wm + mi * 16 + lg * 4;
      if (sg.om == 0){
        short* C = (short*)sg.C;
        #pragma unroll
        for (int j = 0; j < 4; ++j)
          C[(size_t)(mb + j) * 1024 + n] = f2bf(acc[mi][ni][j] + bv);
      } else if (sg.om == 1){
        short* C = (short*)sg.C;
        const int bb = mb / sg.S, sb = mb % sg.S;
        const int hh = n >> 6, dk = n & 63;
        s16x4 pk;
        #pragma unroll
        for (int j = 0; j < 4; ++j) pk[j] = f2bf(acc[mi][ni][j] + bv);
        *(s16x4*)&C[(((size_t)bb * 16 + hh) * 64 + dk) * sg.S + sb] = pk;
      } else {
        float* C = (float*)sg.C;
        #pragma unroll
        for (int j = 0; j < 4; ++j)
          C[(size_t)(mb + j) * 1024 + n] = acc[mi][ni][j] + bv;
      }
    }
  }
}

__device__ __forceinline__ void cvt_core(const float* __restrict__ in,
                                         short* __restrict__ out, int n8){
  const long long total = (long long)gridDim.x * gridDim.y * 256;
  for (long long i = (long long)(blockIdx.y * gridDim.x + blockIdx.x) * 256 + threadIdx.x;
       i < n8; i += total){
    const float4* p = (const float4*)in + i * 2;
    const float4 a = p[0], b = p[1];
    bf16x8 v;
    v[0] = f2bf(a.x); v[1] = f2bf(a.y); v[2] = f2bf(a.z); v[3] = f2bf(a.w);
    v[4] = f2bf(b.x); v[5] = f2bf(b.y); v[6] = f2bf(b.z); v[7] = f2bf(b.w);
    *(bf16x8*)(out + i * 8) = v;
  }
}

__device__ __forceinline__ void bits_core(const int* __restrict__ mask,
                                          const int* __restrict__ pad,
                                          unsigned* __restrict__ bits,
                                          int SK, int nsb, int nunits){
  const int nb = gridDim.x * gridDim.y;
  for (int u = blockIdx.y * gridDim.x + blockIdx.x; u < nunits; u += nb){
    const int row = u / nsb, sb = u - row * nsb;   // row = b*512+q
    const int s = sb * 256 + threadIdx.x;
    const int b = row >> 9;
    const bool v = (mask[(size_t)row * SK + s] != 0) || (pad[(size_t)b * SK + s] != 0);
    unsigned long long bal = __ballot(v);
    const int lane = threadIdx.x & 63;
    if ((lane & 31) == 0)
      bits[((size_t)row * SK + s) >> 5] = (unsigned)(bal >> (lane & 32));
  }
}

__global__ __launch_bounds__(256) void mixk(Big big){
  __shared__ short sA[2][4096];
  __shared__ short sB[2][4096];
  const int a = big.act[blockIdx.z];
  if (a < 4)        gemm_core(big.g[a], sA, sB);
  else if (a < 8)   cvt_core(big.cin[a - 4], big.cout[a - 4], big.n8[a - 4]);
  else if (a == 8)  bits_core(big.me, big.pe, big.be, 512, 2, 16384);
  else if (a == 9)  bits_core(big.mi, big.pi, big.bi, 768, 3, 24576);
  else              pack_core(big);
}

// ---------------------------------------------------------------------------
// One attention modality (8-wave block, 128 q-rows), accumulating wgt*O into
// tot. K/V staging double-buffered (R14-verified; NO setprio -- lockstep
// 8-wave blocks are the m190 regime where it hurts). Even NT => phase
// prologues target buf0 with no cross-phase WAR.
// No-max softmax (Q pre-scaled by 0.125; masked -1e30 -> exp == 0; l==0
// guarded). aw stores nontemporal.
// SINGLE=false: two-phase (P1: l only; P2: recompute + aw + PV). aw written.
// SINGLE=true : single-pass, no aw, unnormalized PV, normalize at end.
// ---------------------------------------------------------------------------
template<int SK, bool HAS_BIAS, bool SINGLE>
__device__ __forceinline__ void attn_mod(
    const short* __restrict__ Kp, const short* __restrict__ Vt,
    const unsigned* __restrict__ bits, float* __restrict__ aw,
    const bf16x8 (&qf)[2], f32x4 (&tot)[4], float wgt,
    short* sK, short* sV, short* sPw,
    int b, int h, int qw, int w, int lane, int lr, int lg){
  constexpr int NT  = SK / 128;
  constexpr int SKW = SK / 32;
  static_assert((NT & 1) == 0, "buffer-parity argument needs even NT");

  const int kchunk = (lane & 7) ^ ((lane >> 3) & 7);
  const short* Ksrc = Kp + ((size_t)b * SK + w * 16 + (lane >> 3)) * 1024 + h * 64 + kchunk * 8;
  const short* Vsrc = Vt + ((size_t)(b * 16 + h)) * 64 * SK;
  const int ldoff = w * 1024 + lane * 8;

  const unsigned* bitrow[4];
  if (HAS_BIAS){
    #pragma unroll
    for (int j = 0; j < 4; ++j)
      bitrow[j] = bits + ((size_t)(b * 512 + qw + lg * 4 + j)) * SKW;
  }

  float lrow[4];
  #pragma unroll
  for (int j = 0; j < 4; ++j) lrow[j] = 0.f;
  f32x4 acco[4] = {};

#define SKB(c) (sK + (c) * 8192)
#define SVB(c) (sV + (c) * 8192)
#define STAGE_K(c, s0) do{ \
    g2l16(Ksrc + (size_t)(s0) * 1024, SKB(c) + ldoff); \
    g2l16(Ksrc + (size_t)((s0) + 8) * 1024, SKB(c) + ldoff + 512); }while(0)
#define STAGE_V(c, s0) do{ \
    const int dd0 = w * 8 + (lane >> 4); \
    const int cg0 = (lane & 15) ^ (dd0 & 15); \
    g2l16(Vsrc + (size_t)dd0 * SK + (s0) + cg0 * 8, SVB(c) + ldoff); \
    const int dd1 = dd0 + 4; \
    const int cg1 = (lane & 15) ^ (dd1 & 15); \
    g2l16(Vsrc + (size_t)dd1 * SK + (s0) + cg1 * 8, SVB(c) + ldoff + 512); }while(0)

  if (!SINGLE){
    // ---------------- Phase 1: row-sum l only (K dbuf) ----------------
    STAGE_K(0, 0);
    int cur = 0;
    for (int tt = 0; tt < NT; ++tt){
      __syncthreads();                    // buf[cur] ready
      if (tt + 1 < NT) STAGE_K(cur ^ 1, (tt + 1) * 128);
      const short* kb = SKB(cur);

      f32x4 accs[8];
      #pragma unroll
      for (int si = 0; si < 8; ++si){
        f32x4 a = {};
        #pragma unroll
        for (int dt = 0; dt < 2; ++dt){
          bf16x8 kf = *(const bf16x8*)&kb[(si * 16 + lr) * 64 + ((dt * 4 + lg) ^ (lr & 7)) * 8];
          a = __builtin_amdgcn_mfma_f32_16x16x32_bf16(qf[dt], kf, a, 0, 0, 0);
        }
        accs[si] = a;
      }

      #pragma unroll
      for (int j = 0; j < 4; ++j){
        unsigned wb[4];
        if (HAS_BIAS){
          #pragma unroll
          for (int sp = 0; sp < 4; ++sp) wb[sp] = bitrow[j][tt * 4 + sp];
        }
        float ssum = 0.f;
        #pragma unroll
        for (int si = 0; si < 8; ++si){
          float v = accs[si][j];
          if (HAS_BIAS && ((wb[si >> 1] >> ((si & 1) * 16 + lr)) & 1u)) v = -1e30f;
          ssum += __expf(v);
        }
        lrow[j] += ssum;
      }
      cur ^= 1;
    }

    // merge l across the 16 lr lanes
    #pragma unroll
    for (int j = 0; j < 4; ++j){
      #pragma unroll
      for (int d = 1; d < 16; d <<= 1) lrow[j] += __shfl_xor(lrow[j], d);
    }
    float rinv[4];
    #pragma unroll
    for (int j = 0; j < 4; ++j) rinv[j] = lrow[j] > 0.f ? 1.0f / lrow[j] : 0.f;

    // ---------------- Phase 2: aw + PV (K+V dbuf) ----------------
    STAGE_K(0, 0);
    STAGE_V(0, 0);
    cur = 0;
    for (int tt = 0; tt < NT; ++tt){
      const int s0 = tt * 128;
      __syncthreads();
      if (tt + 1 < NT){ STAGE_K(cur ^ 1, s0 + 128); STAGE_V(cur ^ 1, s0 + 128); }
      const short* kb = SKB(cur);
      const short* vb = SVB(cur);

      f32x4 accs[8];
      #pragma unroll
      for (int si = 0; si < 8; ++si){
        f32x4 a = {};
        #pragma unroll
        for (int dt = 0; dt < 2; ++dt){
          bf16x8 kf = *(const bf16x8*)&kb[(si * 16 + lr) * 64 + ((dt * 4 + lg) ^ (lr & 7)) * 8];
          a = __builtin_amdgcn_mfma_f32_16x16x32_bf16(qf[dt], kf, a, 0, 0, 0);
        }
        accs[si] = a;
      }

      #pragma unroll
      for (int half = 0; half < 2; ++half){
        #pragma unroll
        for (int j = 0; j < 4; ++j){
          unsigned wb[2];
          if (HAS_BIAS){
            #pragma unroll
            for (int sp = 0; sp < 2; ++sp) wb[sp] = bitrow[j][tt * 4 + half * 2 + sp];
          }
          const int qq = lg * 4 + j;
          float* awrow = aw + (((size_t)(b * 16 + h)) * 512 + qw + qq) * SK + s0 + half * 64 + lr;
          #pragma unroll
          for (int si2 = 0; si2 < 4; ++si2){
            const int si = half * 4 + si2;
            float v = accs[si][j];
            if (HAS_BIAS && ((wb[si2 >> 1] >> ((si2 & 1) * 16 + lr)) & 1u)) v = -1e30f;
            const float p = __expf(v) * rinv[j];
            __builtin_nontemporal_store(p, &awrow[si2 * 16]);
            sPw[qq * 64 + (((si2 * 2 + (lr >> 3)) ^ (qq & 7)) * 8) + (lr & 7)] = f2bf(p);
          }
        }
        // PV half (same-wave LDS write->read; DS ops are in-order)
        #pragma unroll
        for (int kt2 = 0; kt2 < 2; ++kt2){
          const int kt = half * 2 + kt2;
          bf16x8 pa = *(const bf16x8*)&sPw[lr * 64 + (((kt2 * 4 + lg) ^ (lr & 7)) * 8)];
          #pragma unroll
          for (int ni = 0; ni < 4; ++ni){
            bf16x8 vf = *(const bf16x8*)&vb[(ni * 16 + lr) * 128 + ((kt * 4 + lg) ^ lr) * 8];
            acco[ni] = __builtin_amdgcn_mfma_f32_16x16x32_bf16(pa, vf, acco[ni], 0, 0, 0);
          }
        }
      }
      cur ^= 1;
    }

    #pragma unroll
    for (int ni = 0; ni < 4; ++ni)
      #pragma unroll
      for (int j = 0; j < 4; ++j)
        tot[ni][j] += wgt * acco[ni][j];
  } else {
    // ---------------- single-pass, unnormalized PV (K+V dbuf) ----------------
    STAGE_K(0, 0);
    STAGE_V(0, 0);
    int cur = 0;
    for (int tt = 0; tt < NT; ++tt){
      const int s0 = tt * 128;
      __syncthreads();
      if (tt + 1 < NT){ STAGE_K(cur ^ 1, s0 + 128); STAGE_V(cur ^ 1, s0 + 128); }
      const short* kb = SKB(cur);
      const short* vb = SVB(cur);

      f32x4 accs[8];
      #pragma unroll
      for (int si = 0; si < 8; ++si){
        f32x4 a = {};
        #pragma unroll
        for (int dt = 0; dt < 2; ++dt){
          bf16x8 kf = *(const bf16x8*)&kb[(si * 16 + lr) * 64 + ((dt * 4 + lg) ^ (lr & 7)) * 8];
          a = __builtin_amdgcn_mfma_f32_16x16x32_bf16(qf[dt], kf, a, 0, 0, 0);
        }
        accs[si] = a;
      }

      #pragma unroll
      for (int half = 0; half < 2; ++half){
        #pragma unroll
        for (int j = 0; j < 4; ++j){
          unsigned wb[2];
          if (HAS_BIAS){
            #pragma unroll
            for (int sp = 0; sp < 2; ++sp) wb[sp] = bitrow[j][tt * 4 + half * 2 + sp];
          }
          const int qq = lg * 4 + j;
          float ls = 0.f;
          #pragma unroll
          for (int si2 = 0; si2 < 4; ++si2){
            const int si = half * 4 + si2;
            float v = accs[si][j];
            if (HAS_BIAS && ((wb[si2 >> 1] >> ((si2 & 1) * 16 + lr)) & 1u)) v = -1e30f;
            const float p = __expf(v);
            ls += p;
            sPw[qq * 64 + (((si2 * 2 + (lr >> 3)) ^ (qq & 7)) * 8) + (lr & 7)] = f2bf(p);
          }
          lrow[j] += ls;
        }
        #pragma unroll
        for (int kt2 = 0; kt2 < 2; ++kt2){
          const int kt = half * 2 + kt2;
          bf16x8 pa = *(const bf16x8*)&sPw[lr * 64 + (((kt2 * 4 + lg) ^ (lr & 7)) * 8)];
          #pragma unroll
          for (int ni = 0; ni < 4; ++ni){
            bf16x8 vf = *(const bf16x8*)&vb[(ni * 16 + lr) * 128 + ((kt * 4 + lg) ^ lr) * 8];
            acco[ni] = __builtin_amdgcn_mfma_f32_16x16x32_bf16(pa, vf, acco[ni], 0, 0, 0);
          }
        }
      }
      cur ^= 1;
    }

    // final normalize
    #pragma unroll
    for (int j = 0; j < 4; ++j){
      #pragma unroll
      for (int d = 1; d < 16; d <<= 1) lrow[j] += __shfl_xor(lrow[j], d);
      const float r = lrow[j] > 0.f ? wgt / lrow[j] : 0.f;
      #pragma unroll
      for (int ni = 0; ni < 4; ++ni) tot[ni][j] += r * acco[ni][j];
    }
  }
#undef SKB
#undef SVB
#undef STAGE_K
#undef STAGE_V
}

// ---------------------------------------------------------------------------
// Fused attention: all three modalities per block; concat written directly.
// Block = (b, h, 128 q-rows), 8 waves, 512 threads, 80 KB LDS (2 blocks/CU).
// XCD-aware bid decode: same-(b,h) blocks differ by 256 (= 0 mod 8).
// ---------------------------------------------------------------------------
__global__ __launch_bounds__(512)
void attn_fused(const short* __restrict__ Qp,
                const short* __restrict__ Kep, const short* __restrict__ Vte,
                const unsigned* __restrict__ bits_e, float* __restrict__ aw_e,
                const short* __restrict__ Kip, const short* __restrict__ Vti,
                float* __restrict__ aw_i,
                const short* __restrict__ Keip, const short* __restrict__ Vtei,
                const unsigned* __restrict__ bits_ei,
                short* __restrict__ concat){
  __shared__ short sK[2 * 8192];  // 32 KB
  __shared__ short sV[2 * 8192];  // 32 KB
  __shared__ short sP[8192];      // 16 KB (2 KB per wave)

  const int bid = blockIdx.x;
  const int qt = bid >> 8;               // 0..3
  const int g  = bid & 255;              // b*16+h ; same g -> same XCD
  const int h = g & 15, b = g >> 4;
  const int q0 = qt * 128;
  const int t = threadIdx.x, w = t >> 6, lane = t & 63;
  const int lr = lane & 15, lg = lane >> 4;
  const int qw = q0 + w * 16;
  short* sPw = sP + w * 1024;

  // Q fragments (shared by all three modalities; Q pre-scaled by 0.125)
  const short* Qb = Qp + ((size_t)(b * 512 + qw + lr)) * 1024 + h * 64;
  bf16x8 qf[2];
  qf[0] = *(const bf16x8*)&Qb[lg * 8];
  qf[1] = *(const bf16x8*)&Qb[32 + lg * 8];

  f32x4 tot[4] = {};

  attn_mod<512, true , false>(Kep,  Vte,  bits_e,  aw_e, qf, tot, 1.0f,
                              sK, sV, sPw, b, h, qw, w, lane, lr, lg);
  attn_mod<256, false, false>(Kip,  Vti,  nullptr, aw_i, qf, tot, 0.5f,
                              sK, sV, sPw, b, h, qw, w, lane, lr, lg);
  attn_mod<768, true , true >(Keip, Vtei, bits_ei, nullptr, qf, tot, 0.5f,
                              sK, sV, sPw, b, h, qw, w, lane, lr, lg);

  // epilogue: concat = bf16(tot)
  #pragma unroll
  for (int ni = 0; ni < 4; ++ni)
    #pragma unroll
    for (int j = 0; j < 4; ++j){
      const size_t addr = ((size_t)(b * 512 + qw + lg * 4 + j)) * 1024 + h * 64 + ni * 16 + lr;
      concat[addr] = f2bf(tot[ni][j]);
    }
}

// ---------------------------------------------------------------------------
extern "C" void kernel_launch(void* const* d_in, const int* in_sizes, int n_in,
                              void* d_out, int out_size, void* d_ws, size_t ws_size,
                              hipStream_t stream){
  const float* q    = (const float*)d_in[0];
  const float* k_e  = (const float*)d_in[1];
  const float* v_e  = (const float*)d_in[2];
  const float* k_i  = (const float*)d_in[3];
  const float* v_i  = (const float*)d_in[4];
  const float* k_ei = (const float*)d_in[5];
  const float* v_ei = (const float*)d_in[6];
  const int* mask_e  = (const int*)d_in[7];
  const int* mask_ei = (const int*)d_in[8];
  const int* pad_e   = (const int*)d_in[9];
  const int* pad_ei  = (const int*)d_in[10];
  const float* Wq   = (const float*)d_in[11]; const float* bq   = (const float*)d_in[12];
  const float* Wke  = (const float*)d_in[13]; const float* bke  = (const float*)d_in[14];
  const float* Wve  = (const float*)d_in[15]; const float* bve  = (const float*)d_in[16];
  const float* Wki  = (const float*)d_in[17]; const float* bki  = (const float*)d_in[18];
  const float* Wvi  = (const float*)d_in[19]; const float* bvi  = (const float*)d_in[20];
  const float* Wkei = (const float*)d_in[21]; const float* bkei = (const float*)d_in[22];
  const float* Wvei = (const float*)d_in[23]; const float* bvei = (const float*)d_in[24];
  const float* Wout = (const float*)d_in[25]; const float* bout = (const float*)d_in[26];

  char* ws = (char*)d_ws;
  const size_t MB = 1048576;
  // [0,16)   PW ; [16,64) StA -> Kip[16,24) Vti[24,32) Keip[32,56) bits[56,61)
  // [64,128) StB0/StB1/StC0/StC1 -> concat[64,80)
  // [128,176) Qp/Kep/Vte ; [176,200) Vtei   (200 MB total)
  short* PW   = (short*)(ws);
  short* StA0 = (short*)(ws + 16 * MB);
  short* StA1 = (short*)(ws + 32 * MB);
  short* StA2 = (short*)(ws + 48 * MB);
  short* Kip  = (short*)(ws + 16 * MB);
  short* Vti  = (short*)(ws + 24 * MB);
  short* Keip = (short*)(ws + 32 * MB);
  unsigned* bits_e  = (unsigned*)(ws + 56 * MB);
  unsigned* bits_ei = (unsigned*)(ws + 58 * MB);
  short* StB0 = (short*)(ws + 64 * MB);
  short* StB1 = (short*)(ws + 72 * MB);
  short* StC0 = (short*)(ws + 80 * MB);
  short* StC1 = (short*)(ws + 104 * MB);
  short* concat = (short*)(ws + 64 * MB);
  short* Qp   = (short*)(ws + 128 * MB);
  short* Kep  = (short*)(ws + 144 * MB);
  short* Vte  = (short*)(ws + 160 * MB);
  short* Vtei = (short*)(ws + 176 * MB);

  float* out0 = (float*)d_out;
  float* aw_e = out0 + 8388608;
  float* aw_i = out0 + 75497472;

  Big bg{};
  bg.me = mask_e;  bg.pe = pad_e;  bg.be = bits_e;
  bg.mi = mask_ei; bg.pi = pad_ei; bg.bi = bits_ei;
  bg.wsrc[0] = Wq;  bg.wsrc[1] = Wke;  bg.wsrc[2] = Wve;  bg.wsrc[3] = Wki;
  bg.wsrc[4] = Wvi; bg.wsrc[5] = Wkei; bg.wsrc[6] = Wvei; bg.wsrc[7] = Wout;
  bg.pwout = PW;

  // L1+L2 merged: pack (z0, x=tile 0..255, y=weight 0..7)  ||  cvt A (z1-3)
  {
    Big c = bg;
    c.cin[0] = q;   c.cout[0] = StA0; c.n8[0] = 1048576;
    c.cin[1] = k_e; c.cout[1] = StA1; c.n8[1] = 1048576;
    c.cin[2] = v_e; c.cout[2] = StA2; c.n8[2] = 1048576;
    c.act[0] = 10; c.act[1] = 4; c.act[2] = 5; c.act[3] = 6;
    mixk<<<dim3(256, 8, 4), 256, 0, stream>>>(c);
  }
  // L3: gemm A (z0-2)  ||  cvt B/C (z3-6)
  {
    Big c = bg;
    c.g[0] = {StA0, PW + 0 * 1048576, bq,  Qp,  0, 512, 64, 0.125f};
    c.g[1] = {StA1, PW + 1 * 1048576, bke, Kep, 0, 512, 64, 1.0f};
    c.g[2] = {StA2, PW + 2 * 1048576, bve, Vte, 1, 512, 64, 1.0f};
    c.cin[0] = k_i;  c.cout[0] = StB0; c.n8[0] = 524288;
    c.cin[1] = v_i;  c.cout[1] = StB1; c.n8[1] = 524288;
    c.cin[2] = k_ei; c.cout[2] = StC0; c.n8[2] = 1572864;
    c.cin[3] = v_ei; c.cout[3] = StC1; c.n8[3] = 1572864;
    c.act[0] = 0; c.act[1] = 1; c.act[2] = 2;
    c.act[3] = 4; c.act[4] = 5; c.act[5] = 6; c.act[6] = 7;
    mixk<<<dim3(96, 8, 7), 256, 0, stream>>>(c);
  }
  // L4: gemm B/C (z0-3)  ||  bits (z4-5)
  {
    Big c = bg;
    c.g[0] = {StB0, PW + 3 * 1048576, bki,  Kip,  0, 256, 32, 1.0f};
    c.g[1] = {StB1, PW + 4 * 1048576, bvi,  Vti,  1, 256, 32, 1.0f};
    c.g[2] = {StC0, PW + 5 * 1048576, bkei, Keip, 0, 768, 96, 1.0f};
    c.g[3] = {StC1, PW + 6 * 1048576, bvei, Vtei, 1, 768, 96, 1.0f};
    c.act[0] = 0; c.act[1] = 1; c.act[2] = 2; c.act[3] = 3;
    c.act[4] = 8; c.act[5] = 9;
    mixk<<<dim3(96, 8, 6), 256, 0, stream>>>(c);
  }

  // L5: fused attention
  attn_fused<<<1024, 512, 0, stream>>>(Qp, Kep, Vte, bits_e, aw_e,
                                       Kip, Vti, aw_i, Keip, Vtei, bits_ei, concat);

  // L6: output GEMM
  {
    Big c = bg;
    c.g[0] = {concat, PW + 7 * 1048576, bout, out0, 2, 512, 64, 1.0f};
    c.act[0] = 0;
    mixk<<<dim3(64, 8, 1), 256, 0, stream>>>(c);
  }
}